// Round 10
// baseline (217.642 us; speedup 1.0000x reference)
//
#include <hip/hip_runtime.h>

#define B_ 2
#define N_ 2048
#define H_ 8
#define DH_ 32
#define E_ 65536
#define DIN_ 256
#define KT 256
#define ECAP 32
#define QSCALE 0.2550348872f           // log2(e)/sqrt(DH)
#define LOG2E 1.4426950408889634f
#define LOG2MIN -19.931568569324174f   // log2(1e-6)

typedef short bf16x8 __attribute__((ext_vector_type(8)));
typedef float floatx4 __attribute__((ext_vector_type(4)));

__device__ __forceinline__ unsigned short f2b(float f){
  union { float f; unsigned int u; } v; v.f = f;
  return (unsigned short)((v.u + 0x7fffu + ((v.u >> 16) & 1u)) >> 16);
}
__device__ __forceinline__ bf16x8 f8_to_bf(const float* p){
  float4 a = *(const float4*)p, b = *(const float4*)(p + 4);
  bf16x8 r;
  r[0] = (short)f2b(a.x); r[1] = (short)f2b(a.y); r[2] = (short)f2b(a.z); r[3] = (short)f2b(a.w);
  r[4] = (short)f2b(b.x); r[5] = (short)f2b(b.y); r[6] = (short)f2b(b.z); r[7] = (short)f2b(b.w);
  return r;
}
__device__ __forceinline__ unsigned int cvt_pk_bf16(float lo, float hi){
  unsigned int r;
  asm("v_cvt_pk_bf16_f32 %0, %1, %2" : "=v"(r) : "v"(lo), "v"(hi));
  return r;
}
__device__ __forceinline__ float fexp2(float x){
  float r;
  asm("v_exp_f32 %0, %1" : "=v"(r) : "v"(x));
  return r;
}

// ---- prep: ffn (0..511) + fill (512..1023) + wT (1024..1279) + x->bf16 (1280..1791) ----
__global__ __launch_bounds__(256) void prep_kernel(
    const float* __restrict__ eattr,
    const float* __restrict__ w1, const float* __restrict__ b1,
    const float* __restrict__ w2, const float* __restrict__ b2,
    float* __restrict__ ea,
    const int* __restrict__ ei, int* __restrict__ cnt, unsigned int* __restrict__ pck,
    const float* __restrict__ w, unsigned short* __restrict__ wT,
    const float* __restrict__ x, unsigned short* __restrict__ xb)
{
  int bb = blockIdx.x, tid = threadIdx.x;
  if (bb < 512){
    __shared__ float W1[64], W2[64], Bv1[8], Bv2[8];
    if (tid < 64){ W1[tid] = w1[tid]; W2[tid] = w2[tid]; }
    if (tid < 8){ Bv1[tid] = b1[tid]; Bv2[tid] = b2[tid]; }
    __syncthreads();
    int gid = bb * 256 + tid;                 // b*E + e
    const float* ep = eattr + (size_t)gid * 8;
    float cur[8];
#pragma unroll
    for (int i = 0; i < 8; ++i) cur[i] = ep[i];
#pragma unroll
    for (int pass = 0; pass < 2; ++pass){
      float t[8];
#pragma unroll
      for (int j = 0; j < 8; ++j){
        float s = Bv1[j];
#pragma unroll
        for (int i = 0; i < 8; ++i) s += cur[i] * W1[i * 8 + j];
        t[j] = fmaxf(s, 0.f);
      }
#pragma unroll
      for (int j = 0; j < 8; ++j){
        float s = Bv2[j];
#pragma unroll
        for (int i = 0; i < 8; ++i) s += t[i] * W2[i * 8 + j];
        cur[j] = s;
      }
    }
    float* op = ea + (size_t)gid * 8;
#pragma unroll
    for (int j = 0; j < 8; ++j) op[j] = cur[j] * LOG2E;   // exp2-domain
  } else if (bb < 1024){
    int gid = (bb - 512) * 256 + tid;         // 0..131071
    int b = gid >> 16, e = gid & (E_ - 1);
    int u = ei[(size_t)b * 2 * E_ + e];
    int v = ei[(size_t)b * 2 * E_ + E_ + e];
    int bucket = ((b << 11) + u) * 8 + (v >> 8);
    int slot = atomicAdd(&cnt[bucket], 1);
    if (slot < ECAP) pck[(size_t)bucket * ECAP + slot] = ((unsigned int)e << 11) | (unsigned int)v;
  } else if (bb < 1280){
    int k = bb - 1024;                        // 0..255
    for (int c = tid; c < 768; c += 256)
      wT[(size_t)c * 256 + k] = f2b(w[(size_t)k * 768 + c]);
  } else {
    int gid = (bb - 1280) * 256 + tid;        // 0..131071
    bf16x8 v = f8_to_bf(x + (size_t)gid * 8);
    *(bf16x8*)(xb + (size_t)gid * 8) = v;
  }
}

// ---------------- QKV projection: bf16 A-input (pre-converted), MFMA; Q pre-scaled ----------------
__global__ __launch_bounds__(256) void qkv_kernel(
    const unsigned short* __restrict__ xb, const unsigned short* __restrict__ wT,
    const float* __restrict__ bias,
    unsigned short* __restrict__ Qb, unsigned short* __restrict__ Kb, unsigned short* __restrict__ Vt)
{
  int tid = threadIdx.x;
  int wave = tid >> 6, lane = tid & 63, m = lane & 15, quad = lane >> 4;
  int rowbase = blockIdx.x * 16;
  int colbase = blockIdx.y * 64 + wave * 16;
  floatx4 acc = {0.f, 0.f, 0.f, 0.f};
#pragma unroll
  for (int kb = 0; kb < 8; ++kb){
    bf16x8 af = *(const bf16x8*)(xb + (size_t)(rowbase + m) * DIN_ + kb * 32 + quad * 8);
    bf16x8 bf = *(const bf16x8*)(wT + (size_t)(colbase + m) * DIN_ + kb * 32 + quad * 8);
    acc = __builtin_amdgcn_mfma_f32_16x16x32_bf16(af, bf, acc, 0, 0, 0);
  }
  int ccol = colbase + m;
  int which = ccol >> 8, hh = (ccol >> 5) & 7, dh = ccol & 31;
  float bv = bias[ccol];
  int row0 = rowbase + quad * 4;
  int bidx = row0 >> 11, n0 = row0 & (N_ - 1);
  size_t bh = (size_t)(bidx * H_ + hh);
  if (which == 0){
#pragma unroll
    for (int r = 0; r < 4; ++r)
      Qb[(bh * N_ + n0 + r) * DH_ + dh] = f2b((acc[r] + bv) * QSCALE);
  } else if (which == 1){
#pragma unroll
    for (int r = 0; r < 4; ++r)
      Kb[(bh * N_ + n0 + r) * DH_ + dh] = f2b(acc[r] + bv);
  } else {
    ushort4 st;
    st.x = f2b(acc[0] + bv); st.y = f2b(acc[1] + bv);
    st.z = f2b(acc[2] + bv); st.w = f2b(acc[3] + bv);
    *(ushort4*)(Vt + (bh * DH_ + dh) * N_ + n0) = st;
  }
}

// ------------- fused flash attention: in-WG split-K, 4 waves = 2 heads x 2 k-halves -------------
// 1024 WGs x 256 threads. Wave w = (hs = w&1, kh = w>>1): head hp*2+hs, k-range kh*1024..+1024
// (4 tiles of 256). 4096 waves total = 16 waves/CU = 4 waves/SIMD -> 2x TLP vs R8/R9.
// Each wave's S-buffer is 16x128 (+4 pad); a 256-col tile is two 128-col passes through it
// (write->read->overwrite; same-wave DS ops are in-order). Softmax/PV still once per 256 cols.
// The two k-half partials (m,l,O) merge 2-way in LDS at kernel end (one __syncthreads total).
__global__ __launch_bounds__(256) void attn_kernel(
    const unsigned short* __restrict__ Qb, const unsigned short* __restrict__ Kb,
    const unsigned short* __restrict__ Vt, const float* __restrict__ adj,
    const float* __restrict__ ea, const int* __restrict__ cnt, const unsigned int* __restrict__ pck,
    const float* __restrict__ shifts, const float* __restrict__ widths,
    const float* __restrict__ selfW, float* __restrict__ out)
{
  __shared__ float S[4][16][132];         // per-wave 16x128 (+4 pad); reused to park O at end
  __shared__ float mfin[4][16], lfin[4][16];

  int bid = blockIdx.x;                   // 0..1023
  int xcd = bid & 7, t = bid >> 3;        // t 0..127
  int hp = t & 3;                         // head pair 0..3
  int bqt = xcd * 32 + (t >> 2);          // 0..255
  int b = bqt >> 7, qt = bqt & 127;
  int qbase = qt * 16;
  int tid = threadIdx.x, wave = tid >> 6, lane = tid & 63, m = lane & 15, quad = lane >> 4;
  int hs = wave & 1, kh = wave >> 1;
  int h = hp * 2 + hs;
  float shift_h = shifts[h];
  float w_h = widths[h];
  float i2w_h = LOG2E / (2.f * w_h * w_h);
  float selfW_h = selfW[h] * LOG2E;
  size_t krow = (size_t)(b * H_ + h) * N_;
  size_t vrow = (size_t)(b * H_ + h) * DH_;
  bf16x8 qfrag = *(const bf16x8*)(Qb + (krow + qbase + m) * DH_ + quad * 8);
  float (*Sw)[132] = S[wave];

  int rr = lane >> 2, sl0 = lane & 3;     // scatter: 4 lanes per q-row
  const int* cntp = cnt + ((size_t)(b * N_) + qbase + rr) * 8;
  const unsigned int* pckp = pck + ((size_t)((b * N_ + qbase + rr) * 8)) * ECAP;
  const float* eabase = ea + (size_t)b * E_ * H_ + h;
  const float* adjp = adj + ((size_t)b * N_ + qbase + m) * N_ + quad * 8;
  const unsigned short* vp0 = Vt + (vrow + m) * N_ + quad * 8;
  const unsigned short* vp1 = Vt + (vrow + 16 + m) * N_ + quad * 8;
  const unsigned short* kp  = Kb + (krow + m) * DH_ + quad * 8;

  floatx4 sh4 = {shift_h, shift_h, shift_h, shift_h};
  floatx4 ni4 = {-i2w_h, -i2w_h, -i2w_h, -i2w_h};
  floatx4 lm4 = {LOG2MIN, LOG2MIN, LOG2MIN, LOG2MIN};
  floatx4 z4  = {0.f, 0.f, 0.f, 0.f};

  float mcur = -1e30f, lcur = 0.f;        // running max / sum for row m over this k-half
  floatx4 oacc0 = z4, oacc1 = z4;

  // ---- scatter pipeline prologue (first tile of this k-half) ----
  int ktg0 = kh * 4;
  int nb_c = cntp[ktg0]; nb_c = nb_c > ECAP ? ECAP : nb_c;
  unsigned int pk0 = pckp[ktg0 * ECAP + sl0];
  unsigned int pk1 = pckp[ktg0 * ECAP + sl0 + 4];
  int vv0_c = (int)(pk0 & (N_ - 1));
  int vv1_c = (int)(pk1 & (N_ - 1));
  bool g0_c = (sl0 < nb_c);
  bool g1_c = (sl0 + 4 < nb_c);
  float ea0_c = 0.f, ea1_c = 0.f;
  if (g0_c) ea0_c = eabase[(size_t)(pk0 >> 11) * H_];
  if (g1_c) ea1_c = eabase[(size_t)(pk1 >> 11) * H_];

  for (int kt = 0; kt < 4; ++kt){
    int ktg = ktg0 + kt;
    int k0 = ktg * KT;
    // ---- prefetch next-tile scatter metadata ----
    int nb_n = 0; unsigned int pk0_n = 0, pk1_n = 0;
    if (kt + 1 < 4){
      nb_n  = cntp[ktg + 1];
      pk0_n = pckp[(ktg + 1) * ECAP + sl0];
      pk1_n = pckp[(ktg + 1) * ECAP + sl0 + 4];
    }
    floatx4 sv[4][4];
    // ---- two 128-col passes through the shared S-buffer ----
#pragma unroll
    for (int p = 0; p < 2; ++p){
      int kw = k0 + p * 128;
      // QK^T for this 128-col window (2 col-blocks of 64)
#pragma unroll
      for (int cb = 0; cb < 2; ++cb){
        const unsigned short* kpb = kp + (size_t)(kw + cb * 64) * DH_;
#pragma unroll
        for (int s = 0; s < 4; ++s){
          bf16x8 kf = *(const bf16x8*)(kpb + (size_t)(s * 16) * DH_);
          floatx4 acc = __builtin_amdgcn_mfma_f32_16x16x32_bf16(qfrag, kf, z4, 0, 0, 0);
#pragma unroll
          for (int r = 0; r < 4; ++r)
            Sw[quad * 4 + r][cb * 64 + s * 16 + m] = acc[r];
        }
      }
      // diagonal self-loop fixup (window-aligned: all 16 rows in or out)
      {
        int dw = qbase - kw;
        if ((unsigned)dw < 128u && lane < 16)
          Sw[lane][dw + lane] += selfW_h;
      }
      // scatter (preloaded edges landing in this window)
      if (g0_c && ((vv0_c - k0) >> 7) == p) Sw[rr][(vv0_c - k0) & 127] += ea0_c;
      if (g1_c && ((vv1_c - k0) >> 7) == p) Sw[rr][(vv1_c - k0) & 127] += ea1_c;
      if (nb_c > 8){                        // rare overflow (Poisson tail)
        for (int slot = sl0 + 8; slot < nb_c; slot += 4){
          unsigned int pkx = pckp[ktg * ECAP + slot];
          int c = (int)(pkx & (N_ - 1)) - k0;
          if ((c >> 7) == p) Sw[rr][c & 127] += eabase[(size_t)(pkx >> 11) * H_];
        }
      }
      // read S rows to regs + moire (reads complete before next pass overwrites: DS in-order)
#pragma unroll
      for (int cb = 0; cb < 2; ++cb){
        int g = p * 2 + cb;
        const float* sp = &Sw[m][cb * 64 + quad * 8];
        sv[g][0] = *(const floatx4*)(sp);
        sv[g][1] = *(const floatx4*)(sp + 4);
        sv[g][2] = *(const floatx4*)(sp + 32);
        sv[g][3] = *(const floatx4*)(sp + 36);
        const float* ap = adjp + kw + cb * 64;
        floatx4 a0 = *(const floatx4*)(ap);
        floatx4 a1 = *(const floatx4*)(ap + 4);
        floatx4 a2 = *(const floatx4*)(ap + 32);
        floatx4 a3 = *(const floatx4*)(ap + 36);
        floatx4 d;
        d = a0 - sh4; sv[g][0] += __builtin_elementwise_max(d * d * ni4, lm4);
        d = a1 - sh4; sv[g][1] += __builtin_elementwise_max(d * d * ni4, lm4);
        d = a2 - sh4; sv[g][2] += __builtin_elementwise_max(d * d * ni4, lm4);
        d = a3 - sh4; sv[g][3] += __builtin_elementwise_max(d * d * ni4, lm4);
      }
    }
    // ---- issue guarded ea loads for next tile ----
    int vv0_n = 0, vv1_n = 0; bool g0_n = false, g1_n = false;
    float ea0_n = 0.f, ea1_n = 0.f;
    if (kt + 1 < 4){
      nb_n = nb_n > ECAP ? ECAP : nb_n;
      vv0_n = (int)(pk0_n & (N_ - 1));
      vv1_n = (int)(pk1_n & (N_ - 1));
      g0_n = (sl0 < nb_n);
      g1_n = (sl0 + 4 < nb_n);
      if (g0_n) ea0_n = eabase[(size_t)(pk0_n >> 11) * H_];
      if (g1_n) ea1_n = eabase[(size_t)(pk1_n >> 11) * H_];
    }
    // ---- row max over all 256 cols (one shuffle chain per tile) ----
    floatx4 mx01 = __builtin_elementwise_max(
        __builtin_elementwise_max(sv[0][0], sv[0][1]),
        __builtin_elementwise_max(sv[0][2], sv[0][3]));
    floatx4 mx23 = __builtin_elementwise_max(
        __builtin_elementwise_max(sv[1][0], sv[1][1]),
        __builtin_elementwise_max(sv[1][2], sv[1][3]));
    floatx4 mx45 = __builtin_elementwise_max(
        __builtin_elementwise_max(sv[2][0], sv[2][1]),
        __builtin_elementwise_max(sv[2][2], sv[2][3]));
    floatx4 mx67 = __builtin_elementwise_max(
        __builtin_elementwise_max(sv[3][0], sv[3][1]),
        __builtin_elementwise_max(sv[3][2], sv[3][3]));
    floatx4 mxv = __builtin_elementwise_max(__builtin_elementwise_max(mx01, mx23),
                                            __builtin_elementwise_max(mx45, mx67));
    float lmx = fmaxf(fmaxf(mxv.x, mxv.y), fmaxf(mxv.z, mxv.w));
    lmx = fmaxf(lmx, __shfl_xor(lmx, 16));
    lmx = fmaxf(lmx, __shfl_xor(lmx, 32));
    float mnew = fmaxf(mcur, lmx);
    float al = fexp2(mcur - mnew);
    mcur = mnew;
    float al0 = __shfl(al, quad * 4 + 0);
    float al1 = __shfl(al, quad * 4 + 1);
    float al2 = __shfl(al, quad * 4 + 2);
    float al3 = __shfl(al, quad * 4 + 3);
    oacc0[0] *= al0; oacc0[1] *= al1; oacc0[2] *= al2; oacc0[3] *= al3;
    oacc1[0] *= al0; oacc1[1] *= al1; oacc1[2] *= al2; oacc1[3] *= al3;
    // ---- P = exp2(S - m), pack, PV MFMA per 64-col group; lane-partial row sum ----
    floatx4 m4 = {mcur, mcur, mcur, mcur};
    floatx4 psv = z4;
#pragma unroll
    for (int g = 0; g < 4; ++g){
      const unsigned short* vA = vp0 + k0 + g * 64;
      const unsigned short* vB = vp1 + k0 + g * 64;
      bf16x8 vf00 = *(const bf16x8*)(vA);
      bf16x8 vf01 = *(const bf16x8*)(vB);
      bf16x8 vf10 = *(const bf16x8*)(vA + 32);
      bf16x8 vf11 = *(const bf16x8*)(vB + 32);
      floatx4 e0 = sv[g][0] - m4, e1 = sv[g][1] - m4;
      floatx4 e2 = sv[g][2] - m4, e3 = sv[g][3] - m4;
      floatx4 p0, p1, p2, p3;
      p0.x = fexp2(e0.x); p0.y = fexp2(e0.y); p0.z = fexp2(e0.z); p0.w = fexp2(e0.w);
      p1.x = fexp2(e1.x); p1.y = fexp2(e1.y); p1.z = fexp2(e1.z); p1.w = fexp2(e1.w);
      p2.x = fexp2(e2.x); p2.y = fexp2(e2.y); p2.z = fexp2(e2.z); p2.w = fexp2(e2.w);
      p3.x = fexp2(e3.x); p3.y = fexp2(e3.y); p3.z = fexp2(e3.z); p3.w = fexp2(e3.w);
      psv += (p0 + p1) + (p2 + p3);
      union { bf16x8 v; unsigned int u[4]; } PL, PH;
      PL.u[0] = cvt_pk_bf16(p0.x, p0.y); PL.u[1] = cvt_pk_bf16(p0.z, p0.w);
      PL.u[2] = cvt_pk_bf16(p1.x, p1.y); PL.u[3] = cvt_pk_bf16(p1.z, p1.w);
      PH.u[0] = cvt_pk_bf16(p2.x, p2.y); PH.u[1] = cvt_pk_bf16(p2.z, p2.w);
      PH.u[2] = cvt_pk_bf16(p3.x, p3.y); PH.u[3] = cvt_pk_bf16(p3.z, p3.w);
      oacc0 = __builtin_amdgcn_mfma_f32_16x16x32_bf16(PL.v, vf00, oacc0, 0, 0, 0);
      oacc1 = __builtin_amdgcn_mfma_f32_16x16x32_bf16(PL.v, vf01, oacc1, 0, 0, 0);
      oacc0 = __builtin_amdgcn_mfma_f32_16x16x32_bf16(PH.v, vf10, oacc0, 0, 0, 0);
      oacc1 = __builtin_amdgcn_mfma_f32_16x16x32_bf16(PH.v, vf11, oacc1, 0, 0, 0);
    }
    float ps = (psv.x + psv.y) + (psv.z + psv.w);
    ps += __shfl_xor(ps, 16);
    ps += __shfl_xor(ps, 32);
    lcur = lcur * al + ps;
    // ---- rotate scatter pipeline ----
    nb_c = nb_n; g0_c = g0_n; g1_c = g1_n;
    vv0_c = vv0_n; vv1_c = vv1_n; ea0_c = ea0_n; ea1_c = ea1_n;
  }

  // ---- 2-way k-half merge in LDS: waves (hs) and (hs+2) share head hp*2+hs ----
  if (quad == 0){ mfin[wave][m] = mcur; lfin[wave][m] = lcur; }
  float* Ow = &S[wave][0][0];             // park O in own region (stride 132)
#pragma unroll
  for (int r = 0; r < 4; ++r){
    Ow[(quad * 4 + r) * 132 + m]      = oacc0[r];
    Ow[(quad * 4 + r) * 132 + 16 + m] = oacc1[r];
  }
  __syncthreads();
#pragma unroll
  for (int ii = 0; ii < 4; ++ii){
    int i = tid + ii * 256;               // 0..1023: 2 heads x 16 rows x 32 dh
    int hs2 = i >> 9, r = (i >> 5) & 15, d = i & 31;
    float m0 = mfin[hs2][r], m1 = mfin[hs2 + 2][r];
    float mg = fmaxf(m0, m1);
    float w0 = fexp2(m0 - mg), w1 = fexp2(m1 - mg);
    float o = S[hs2][r][d] * w0 + S[hs2 + 2][r][d] * w1;
    float l = lfin[hs2][r] * w0 + lfin[hs2 + 2][r] * w1;
    out[((size_t)b * N_ + qbase + r) * (H_ * DH_) + (hp * 2 + hs2) * DH_ + d] = o / l;
  }
}

extern "C" void kernel_launch(void* const* d_in, const int* in_sizes, int n_in,
                              void* d_out, int out_size, void* d_ws, size_t ws_size,
                              hipStream_t stream)
{
  const float* x      = (const float*)d_in[0];
  const float* adj    = (const float*)d_in[1];
  const float* eattr  = (const float*)d_in[2];
  const float* qkvw   = (const float*)d_in[3];
  const float* qkvb   = (const float*)d_in[4];
  const float* ew1    = (const float*)d_in[5];
  const float* eb1    = (const float*)d_in[6];
  const float* ew2    = (const float*)d_in[7];
  const float* eb2    = (const float*)d_in[8];
  const float* shifts = (const float*)d_in[9];
  const float* widths = (const float*)d_in[10];
  const float* selfW  = (const float*)d_in[11];
  const int*   ei     = (const int*)d_in[12];
  float* out = (float*)d_out;

  char* ws = (char*)d_ws;
  unsigned short* Qb  = (unsigned short*)(ws);                        // 2 MB
  unsigned short* Kb  = (unsigned short*)(ws + ((size_t)2 << 20));    // 2 MB
  unsigned short* Vt  = (unsigned short*)(ws + ((size_t)4 << 20));    // 2 MB
  unsigned short* wT  = (unsigned short*)(ws + ((size_t)6 << 20));    // 384 KB
  float*          ea  = (float*)(ws + ((size_t)7 << 20));             // 4 MB
  int*            cnt = (int*)(ws + ((size_t)11 << 20));              // 128 KB
  unsigned int*  pck  = (unsigned int*)(ws + ((size_t)12 << 20));     // 4 MB
  unsigned short* xb  = (unsigned short*)(ws + ((size_t)16 << 20));   // 2 MB (total 18 MB)

  hipMemsetAsync(cnt, 0, (size_t)B_ * N_ * 8 * sizeof(int), stream);
  hipLaunchKernelGGL(prep_kernel, dim3(1792), dim3(256), 0, stream,
                     eattr, ew1, eb1, ew2, eb2, ea, ei, cnt, pck, qkvw, wT, x, xb);
  hipLaunchKernelGGL(qkv_kernel, dim3(256, 12), dim3(256), 0, stream, xb, wT, qkvb, Qb, Kb, Vt);
  hipLaunchKernelGGL(attn_kernel, dim3(B_ * (H_ / 2) * (N_ / 16)), dim3(256), 0, stream,
                     Qb, Kb, Vt, adj, ea, cnt, pck, shifts, widths, selfW, out);
}

// Round 11
// 210.273 us; speedup vs baseline: 1.0350x; 1.0350x over previous
//
#include <hip/hip_runtime.h>

#define B_ 2
#define N_ 2048
#define H_ 8
#define DH_ 32
#define E_ 65536
#define DIN_ 256
#define KT 256
#define NKT (N_ / KT)
#define ECAP 32
#define QSCALE 0.2550348872f           // log2(e)/sqrt(DH)
#define LOG2E 1.4426950408889634f
#define LOG2MIN -19.931568569324174f   // log2(1e-6)

typedef short bf16x8 __attribute__((ext_vector_type(8)));
typedef float floatx4 __attribute__((ext_vector_type(4)));

__device__ __forceinline__ unsigned short f2b(float f){
  union { float f; unsigned int u; } v; v.f = f;
  return (unsigned short)((v.u + 0x7fffu + ((v.u >> 16) & 1u)) >> 16);
}
__device__ __forceinline__ bf16x8 f8_to_bf(const float* p){
  float4 a = *(const float4*)p, b = *(const float4*)(p + 4);
  bf16x8 r;
  r[0] = (short)f2b(a.x); r[1] = (short)f2b(a.y); r[2] = (short)f2b(a.z); r[3] = (short)f2b(a.w);
  r[4] = (short)f2b(b.x); r[5] = (short)f2b(b.y); r[6] = (short)f2b(b.z); r[7] = (short)f2b(b.w);
  return r;
}
__device__ __forceinline__ unsigned int cvt_pk_bf16(float lo, float hi){
  unsigned int r;
  asm("v_cvt_pk_bf16_f32 %0, %1, %2" : "=v"(r) : "v"(lo), "v"(hi));
  return r;
}
__device__ __forceinline__ float fexp2(float x){
  float r;
  asm("v_exp_f32 %0, %1" : "=v"(r) : "v"(x));
  return r;
}

// ---- prep: ffn (0..511) + fill (512..1023) + wT (1024..1279, coalesced writes) + x->bf16 (1280..1791) ----
__global__ __launch_bounds__(256) void prep_kernel(
    const float* __restrict__ eattr,
    const float* __restrict__ w1, const float* __restrict__ b1,
    const float* __restrict__ w2, const float* __restrict__ b2,
    float* __restrict__ ea,
    const int* __restrict__ ei, int* __restrict__ cnt, unsigned int* __restrict__ pck,
    const float* __restrict__ w, unsigned short* __restrict__ wT,
    const float* __restrict__ x, unsigned short* __restrict__ xb)
{
  int bb = blockIdx.x, tid = threadIdx.x;
  if (bb < 512){
    __shared__ float W1[64], W2[64], Bv1[8], Bv2[8];
    if (tid < 64){ W1[tid] = w1[tid]; W2[tid] = w2[tid]; }
    if (tid < 8){ Bv1[tid] = b1[tid]; Bv2[tid] = b2[tid]; }
    __syncthreads();
    int gid = bb * 256 + tid;                 // b*E + e
    const float* ep = eattr + (size_t)gid * 8;
    float cur[8];
#pragma unroll
    for (int i = 0; i < 8; ++i) cur[i] = ep[i];
#pragma unroll
    for (int pass = 0; pass < 2; ++pass){
      float t[8];
#pragma unroll
      for (int j = 0; j < 8; ++j){
        float s = Bv1[j];
#pragma unroll
        for (int i = 0; i < 8; ++i) s += cur[i] * W1[i * 8 + j];
        t[j] = fmaxf(s, 0.f);
      }
#pragma unroll
      for (int j = 0; j < 8; ++j){
        float s = Bv2[j];
#pragma unroll
        for (int i = 0; i < 8; ++i) s += t[i] * W2[i * 8 + j];
        cur[j] = s;
      }
    }
    float* op = ea + (size_t)gid * 8;
#pragma unroll
    for (int j = 0; j < 8; ++j) op[j] = cur[j] * LOG2E;   // exp2-domain
  } else if (bb < 1024){
    int gid = (bb - 512) * 256 + tid;         // 0..131071
    int b = gid >> 16, e = gid & (E_ - 1);
    int u = ei[(size_t)b * 2 * E_ + e];
    int v = ei[(size_t)b * 2 * E_ + E_ + e];
    int bucket = ((b << 11) + u) * 8 + (v >> 8);
    int slot = atomicAdd(&cnt[bucket], 1);
    if (slot < ECAP) pck[(size_t)bucket * ECAP + slot] = ((unsigned int)e << 11) | (unsigned int)v;
  } else if (bb < 1280){
    // wT transpose, write-coalesced: block owns 3 full columns; thread k = tid writes
    // 512 B contiguous per column (no cache-line sharing across blocks). Reads are
    // scattered but w (768 KB) is L2-resident per XCD.
    int c0 = (bb - 1024) * 3;
#pragma unroll
    for (int j = 0; j < 3; ++j){
      int c = c0 + j;
      wT[(size_t)c * 256 + tid] = f2b(w[(size_t)tid * 768 + c]);
    }
  } else {
    int gid = (bb - 1280) * 256 + tid;        // 0..131071
    bf16x8 v = f8_to_bf(x + (size_t)gid * 8);
    *(bf16x8*)(xb + (size_t)gid * 8) = v;
  }
}

// ---------------- QKV projection: bf16 A-input, MFMA; V staged via LDS for coalesced stores ----------------
__global__ __launch_bounds__(256) void qkv_kernel(
    const unsigned short* __restrict__ xb, const unsigned short* __restrict__ wT,
    const float* __restrict__ bias,
    unsigned short* __restrict__ Qb, unsigned short* __restrict__ Kb, unsigned short* __restrict__ Vt)
{
  __shared__ unsigned short vtile[64][20];   // 64 dh-cols x 16 n (+4 pad); 2.5 KB
  int tid = threadIdx.x;
  int wave = tid >> 6, lane = tid & 63, m = lane & 15, quad = lane >> 4;
  int rowbase = blockIdx.x * 16;
  int colbase = blockIdx.y * 64 + wave * 16;
  floatx4 acc = {0.f, 0.f, 0.f, 0.f};
#pragma unroll
  for (int kb = 0; kb < 8; ++kb){
    bf16x8 af = *(const bf16x8*)(xb + (size_t)(rowbase + m) * DIN_ + kb * 32 + quad * 8);
    bf16x8 bf = *(const bf16x8*)(wT + (size_t)(colbase + m) * DIN_ + kb * 32 + quad * 8);
    acc = __builtin_amdgcn_mfma_f32_16x16x32_bf16(af, bf, acc, 0, 0, 0);
  }
  int ccol = colbase + m;
  int which = ccol >> 8, hh = (ccol >> 5) & 7, dh = ccol & 31;
  float bv = bias[ccol];
  int row0 = rowbase + quad * 4;
  int bidx = row0 >> 11, n0 = row0 & (N_ - 1);
  size_t bh = (size_t)(bidx * H_ + hh);
  if (which == 0){
#pragma unroll
    for (int r = 0; r < 4; ++r)
      Qb[(bh * N_ + n0 + r) * DH_ + dh] = f2b((acc[r] + bv) * QSCALE);
  } else if (which == 1){
#pragma unroll
    for (int r = 0; r < 4; ++r)
      Kb[(bh * N_ + n0 + r) * DH_ + dh] = f2b(acc[r] + bv);
  } else {
    // V: stage block's 64x16 tile in LDS, then write transposed with 32 B-contiguous
    // runs per dh-row (4x fewer cache-line touches than direct strided ushort4 stores).
    int dh_b = wave * 16 + m;               // 0..63 (block-local output column)
    int n_l = quad * 4;                     // 0..12 (block-local row)
#pragma unroll
    for (int r = 0; r < 4; ++r)
      vtile[dh_b][n_l + r] = f2b(acc[r] + bv);
    __syncthreads();                        // block-uniform path (y-blocks 8..11 only)
    int dhb2 = tid >> 2;                    // 0..63
    int ng = (tid & 3) * 4;                 // 0,4,8,12
    int cc2 = blockIdx.y * 64 + dhb2;
    int hh2 = (cc2 >> 5) & 7, dh2 = cc2 & 31;
    int bidx2 = rowbase >> 11, nb2 = rowbase & (N_ - 1);
    ushort4 st = *(const ushort4*)&vtile[dhb2][ng];
    *(ushort4*)(Vt + ((size_t)((bidx2 * H_ + hh2) * DH_ + dh2)) * N_ + nb2 + ng) = st;
  }
}

// ---------------- fused flash attention: ONE WAVE = one (b, h, 16 q-rows); unroll-2 (R9, proven) ----------------
__global__ __launch_bounds__(128) void attn_kernel(
    const unsigned short* __restrict__ Qb, const unsigned short* __restrict__ Kb,
    const unsigned short* __restrict__ Vt, const float* __restrict__ adj,
    const float* __restrict__ ea, const int* __restrict__ cnt, const unsigned int* __restrict__ pck,
    const float* __restrict__ shifts, const float* __restrict__ widths,
    const float* __restrict__ selfW, float* __restrict__ out)
{
  __shared__ float S[2][16][260];         // per-wave 16x256 (+4 pad)

  int bid = blockIdx.x;                   // 0..1023
  int xcd = bid & 7, t = bid >> 3;        // t 0..127
  int hp = t & 3;                         // head pair 0..3
  int bqt = xcd * 32 + (t >> 2);          // 0..255
  int b = bqt >> 7, qt = bqt & 127;
  int qbase = qt * 16;
  int tid = threadIdx.x, wave = tid >> 6, lane = tid & 63, m = lane & 15, quad = lane >> 4;
  int h = hp * 2 + wave;
  float shift_h = shifts[h];
  float w_h = widths[h];
  float i2w_h = LOG2E / (2.f * w_h * w_h);
  float selfW_h = selfW[h] * LOG2E;
  size_t krow = (size_t)(b * H_ + h) * N_;
  size_t vrow = (size_t)(b * H_ + h) * DH_;
  bf16x8 qfrag = *(const bf16x8*)(Qb + (krow + qbase + m) * DH_ + quad * 8);
  float (*Sw)[260] = S[wave];

  int rr = lane >> 2, sl0 = lane & 3;     // scatter: 4 lanes per q-row
  const int* cntp = cnt + ((size_t)(b * N_) + qbase + rr) * 8;
  const unsigned int* pckp = pck + ((size_t)((b * N_ + qbase + rr) * 8)) * ECAP;
  const float* eabase = ea + (size_t)b * E_ * H_ + h;
  const float* adjp = adj + ((size_t)b * N_ + qbase + m) * N_ + quad * 8;
  const unsigned short* vp0 = Vt + (vrow + m) * N_ + quad * 8;
  const unsigned short* vp1 = Vt + (vrow + 16 + m) * N_ + quad * 8;
  const unsigned short* kp  = Kb + (krow + m) * DH_ + quad * 8;

  floatx4 sh4 = {shift_h, shift_h, shift_h, shift_h};
  floatx4 ni4 = {-i2w_h, -i2w_h, -i2w_h, -i2w_h};
  floatx4 lm4 = {LOG2MIN, LOG2MIN, LOG2MIN, LOG2MIN};
  floatx4 z4  = {0.f, 0.f, 0.f, 0.f};

  float mcur = -1e30f, lcur = 0.f;
  floatx4 oacc0 = z4, oacc1 = z4;

  // ---- scatter pipeline prologue (tile 0) ----
  int nb_c = cntp[0]; nb_c = nb_c > ECAP ? ECAP : nb_c;
  unsigned int pk0 = pckp[sl0];
  unsigned int pk1 = pckp[sl0 + 4];
  int vv0_c = (int)(pk0 & (N_ - 1));
  int vv1_c = (int)(pk1 & (N_ - 1));
  bool g0_c = (sl0 < nb_c);
  bool g1_c = (sl0 + 4 < nb_c);
  float ea0_c = 0.f, ea1_c = 0.f;
  if (g0_c) ea0_c = eabase[(size_t)(pk0 >> 11) * H_];
  if (g1_c) ea1_c = eabase[(size_t)(pk1 >> 11) * H_];

#pragma unroll 2
  for (int kt = 0; kt < NKT; ++kt){
    int k0 = kt * KT;
    // ---- prefetch next-tile scatter metadata ----
    int nb_n = 0; unsigned int pk0_n = 0, pk1_n = 0;
    if (kt + 1 < NKT){
      nb_n  = cntp[kt + 1];
      pk0_n = pckp[(kt + 1) * ECAP + sl0];
      pk1_n = pckp[(kt + 1) * ECAP + sl0 + 4];
    }
    // ---- QK^T: full 256 cols x 16 rows (4 col-blocks) ----
#pragma unroll
    for (int cb = 0; cb < 4; ++cb){
      const unsigned short* kpb = kp + (size_t)(k0 + cb * 64) * DH_;
#pragma unroll
      for (int s = 0; s < 4; ++s){
        bf16x8 kf = *(const bf16x8*)(kpb + (size_t)(s * 16) * DH_);
        floatx4 acc = __builtin_amdgcn_mfma_f32_16x16x32_bf16(qfrag, kf, z4, 0, 0, 0);
#pragma unroll
        for (int r = 0; r < 4; ++r)
          Sw[quad * 4 + r][cb * 64 + s * 16 + m] = acc[r];
      }
    }
    // ---- diagonal self-loop fixup ----
    {
      int dw = qbase - k0;
      if ((unsigned)dw < 256u && lane < 16)
        Sw[lane][dw + lane] += selfW_h;
    }
    // ---- scatter apply (ea preloaded one tile ago) ----
    if (g0_c) Sw[rr][vv0_c - k0] += ea0_c;
    if (g1_c) Sw[rr][vv1_c - k0] += ea1_c;
    if (nb_c > 8){                          // rare overflow (Poisson tail)
      for (int slot = sl0 + 8; slot < nb_c; slot += 4){
        unsigned int p = pckp[kt * ECAP + slot];
        Sw[rr][(int)(p & (N_ - 1)) - k0] += eabase[(size_t)(p >> 11) * H_];
      }
    }
    // ---- issue guarded ea loads for next tile ----
    int vv0_n = 0, vv1_n = 0; bool g0_n = false, g1_n = false;
    float ea0_n = 0.f, ea1_n = 0.f;
    if (kt + 1 < NKT){
      nb_n = nb_n > ECAP ? ECAP : nb_n;
      vv0_n = (int)(pk0_n & (N_ - 1));
      vv1_n = (int)(pk1_n & (N_ - 1));
      g0_n = (sl0 < nb_n);
      g1_n = (sl0 + 4 < nb_n);
      if (g0_n) ea0_n = eabase[(size_t)(pk0_n >> 11) * H_];
      if (g1_n) ea1_n = eabase[(size_t)(pk1_n >> 11) * H_];
    }
    // ---- S rows to regs + moire, all 4 col-blocks ----
    floatx4 sv[4][4];
#pragma unroll
    for (int cb = 0; cb < 4; ++cb){
      const float* sp = &Sw[m][cb * 64 + quad * 8];
      sv[cb][0] = *(const floatx4*)(sp);
      sv[cb][1] = *(const floatx4*)(sp + 4);
      sv[cb][2] = *(const floatx4*)(sp + 32);
      sv[cb][3] = *(const floatx4*)(sp + 36);
      const float* ap = adjp + k0 + cb * 64;
      floatx4 a0 = *(const floatx4*)(ap);
      floatx4 a1 = *(const floatx4*)(ap + 4);
      floatx4 a2 = *(const floatx4*)(ap + 32);
      floatx4 a3 = *(const floatx4*)(ap + 36);
      floatx4 d;
      d = a0 - sh4; sv[cb][0] += __builtin_elementwise_max(d * d * ni4, lm4);
      d = a1 - sh4; sv[cb][1] += __builtin_elementwise_max(d * d * ni4, lm4);
      d = a2 - sh4; sv[cb][2] += __builtin_elementwise_max(d * d * ni4, lm4);
      d = a3 - sh4; sv[cb][3] += __builtin_elementwise_max(d * d * ni4, lm4);
    }
    // ---- row max over all 256 cols (one shuffle chain per tile) ----
    floatx4 mx01 = __builtin_elementwise_max(
        __builtin_elementwise_max(sv[0][0], sv[0][1]),
        __builtin_elementwise_max(sv[0][2], sv[0][3]));
    floatx4 mx23 = __builtin_elementwise_max(
        __builtin_elementwise_max(sv[1][0], sv[1][1]),
        __builtin_elementwise_max(sv[1][2], sv[1][3]));
    floatx4 mx45 = __builtin_elementwise_max(
        __builtin_elementwise_max(sv[2][0], sv[2][1]),
        __builtin_elementwise_max(sv[2][2], sv[2][3]));
    floatx4 mx67 = __builtin_elementwise_max(
        __builtin_elementwise_max(sv[3][0], sv[3][1]),
        __builtin_elementwise_max(sv[3][2], sv[3][3]));
    floatx4 mxv = __builtin_elementwise_max(__builtin_elementwise_max(mx01, mx23),
                                            __builtin_elementwise_max(mx45, mx67));
    float lm = fmaxf(fmaxf(mxv.x, mxv.y), fmaxf(mxv.z, mxv.w));
    lm = fmaxf(lm, __shfl_xor(lm, 16));
    lm = fmaxf(lm, __shfl_xor(lm, 32));
    float mnew = fmaxf(mcur, lm);
    float al = fexp2(mcur - mnew);
    mcur = mnew;
    float al0 = __shfl(al, quad * 4 + 0);
    float al1 = __shfl(al, quad * 4 + 1);
    float al2 = __shfl(al, quad * 4 + 2);
    float al3 = __shfl(al, quad * 4 + 3);
    oacc0[0] *= al0; oacc0[1] *= al1; oacc0[2] *= al2; oacc0[3] *= al3;
    oacc1[0] *= al0; oacc1[1] *= al1; oacc1[2] *= al2; oacc1[3] *= al3;
    // ---- P = exp2(S - m), pack, PV MFMA per col-block; lane-partial row sum ----
    floatx4 m4 = {mcur, mcur, mcur, mcur};
    floatx4 psv = z4;
#pragma unroll
    for (int cb = 0; cb < 4; ++cb){
      const unsigned short* vA = vp0 + k0 + cb * 64;
      const unsigned short* vB = vp1 + k0 + cb * 64;
      bf16x8 vf00 = *(const bf16x8*)(vA);
      bf16x8 vf01 = *(const bf16x8*)(vB);
      bf16x8 vf10 = *(const bf16x8*)(vA + 32);
      bf16x8 vf11 = *(const bf16x8*)(vB + 32);
      floatx4 e0 = sv[cb][0] - m4, e1 = sv[cb][1] - m4;
      floatx4 e2 = sv[cb][2] - m4, e3 = sv[cb][3] - m4;
      floatx4 p0, p1, p2, p3;
      p0.x = fexp2(e0.x); p0.y = fexp2(e0.y); p0.z = fexp2(e0.z); p0.w = fexp2(e0.w);
      p1.x = fexp2(e1.x); p1.y = fexp2(e1.y); p1.z = fexp2(e1.z); p1.w = fexp2(e1.w);
      p2.x = fexp2(e2.x); p2.y = fexp2(e2.y); p2.z = fexp2(e2.z); p2.w = fexp2(e2.w);
      p3.x = fexp2(e3.x); p3.y = fexp2(e3.y); p3.z = fexp2(e3.z); p3.w = fexp2(e3.w);
      psv += (p0 + p1) + (p2 + p3);
      union { bf16x8 v; unsigned int u[4]; } PL, PH;
      PL.u[0] = cvt_pk_bf16(p0.x, p0.y); PL.u[1] = cvt_pk_bf16(p0.z, p0.w);
      PL.u[2] = cvt_pk_bf16(p1.x, p1.y); PL.u[3] = cvt_pk_bf16(p1.z, p1.w);
      PH.u[0] = cvt_pk_bf16(p2.x, p2.y); PH.u[1] = cvt_pk_bf16(p2.z, p2.w);
      PH.u[2] = cvt_pk_bf16(p3.x, p3.y); PH.u[3] = cvt_pk_bf16(p3.z, p3.w);
      oacc0 = __builtin_amdgcn_mfma_f32_16x16x32_bf16(PL.v, vf00, oacc0, 0, 0, 0);
      oacc1 = __builtin_amdgcn_mfma_f32_16x16x32_bf16(PL.v, vf01, oacc1, 0, 0, 0);
      oacc0 = __builtin_amdgcn_mfma_f32_16x16x32_bf16(PH.v, vf10, oacc0, 0, 0, 0);
      oacc1 = __builtin_amdgcn_mfma_f32_16x16x32_bf16(PH.v, vf11, oacc1, 0, 0, 0);
    }
    float ps = (psv.x + psv.y) + (psv.z + psv.w);
    ps += __shfl_xor(ps, 16);
    ps += __shfl_xor(ps, 32);
    lcur = lcur * al + ps;
    // ---- rotate scatter pipeline ----
    nb_c = nb_n; g0_c = g0_n; g1_c = g1_n;
    vv0_c = vv0_n; vv1_c = vv1_n; ea0_c = ea0_n; ea1_c = ea1_n;
  }

  // ---- direct output (wave owns full rows: no merge, no barrier) ----
  float linv0 = 1.f / __shfl(lcur, quad * 4 + 0);
  float linv1 = 1.f / __shfl(lcur, quad * 4 + 1);
  float linv2 = 1.f / __shfl(lcur, quad * 4 + 2);
  float linv3 = 1.f / __shfl(lcur, quad * 4 + 3);
  float* ob = out + ((size_t)b * N_ + qbase + quad * 4) * (H_ * DH_) + h * DH_;
  ob[0 * H_ * DH_ + m]      = oacc0[0] * linv0;
  ob[0 * H_ * DH_ + 16 + m] = oacc1[0] * linv0;
  ob[1 * H_ * DH_ + m]      = oacc0[1] * linv1;
  ob[1 * H_ * DH_ + 16 + m] = oacc1[1] * linv1;
  ob[2 * H_ * DH_ + m]      = oacc0[2] * linv2;
  ob[2 * H_ * DH_ + 16 + m] = oacc1[2] * linv2;
  ob[3 * H_ * DH_ + m]      = oacc0[3] * linv3;
  ob[3 * H_ * DH_ + 16 + m] = oacc1[3] * linv3;
}

extern "C" void kernel_launch(void* const* d_in, const int* in_sizes, int n_in,
                              void* d_out, int out_size, void* d_ws, size_t ws_size,
                              hipStream_t stream)
{
  const float* x      = (const float*)d_in[0];
  const float* adj    = (const float*)d_in[1];
  const float* eattr  = (const float*)d_in[2];
  const float* qkvw   = (const float*)d_in[3];
  const float* qkvb   = (const float*)d_in[4];
  const float* ew1    = (const float*)d_in[5];
  const float* eb1    = (const float*)d_in[6];
  const float* ew2    = (const float*)d_in[7];
  const float* eb2    = (const float*)d_in[8];
  const float* shifts = (const float*)d_in[9];
  const float* widths = (const float*)d_in[10];
  const float* selfW  = (const float*)d_in[11];
  const int*   ei     = (const int*)d_in[12];
  float* out = (float*)d_out;

  char* ws = (char*)d_ws;
  unsigned short* Qb  = (unsigned short*)(ws);                        // 2 MB
  unsigned short* Kb  = (unsigned short*)(ws + ((size_t)2 << 20));    // 2 MB
  unsigned short* Vt  = (unsigned short*)(ws + ((size_t)4 << 20));    // 2 MB
  unsigned short* wT  = (unsigned short*)(ws + ((size_t)6 << 20));    // 384 KB
  float*          ea  = (float*)(ws + ((size_t)7 << 20));             // 4 MB
  int*            cnt = (int*)(ws + ((size_t)11 << 20));              // 128 KB
  unsigned int*  pck  = (unsigned int*)(ws + ((size_t)12 << 20));     // 4 MB
  unsigned short* xb  = (unsigned short*)(ws + ((size_t)16 << 20));   // 2 MB (total 18 MB)

  hipMemsetAsync(cnt, 0, (size_t)B_ * N_ * 8 * sizeof(int), stream);
  hipLaunchKernelGGL(prep_kernel, dim3(1792), dim3(256), 0, stream,
                     eattr, ew1, eb1, ew2, eb2, ea, ei, cnt, pck, qkvw, wT, x, xb);
  hipLaunchKernelGGL(qkv_kernel, dim3(256, 12), dim3(256), 0, stream, xb, wT, qkvb, Qb, Kb, Vt);
  hipLaunchKernelGGL(attn_kernel, dim3(B_ * (H_ / 2) * (N_ / 16)), dim3(128), 0, stream,
                     Qb, Kb, Vt, adj, ea, cnt, pck, shifts, widths, selfW, out);
}

// Round 12
// 210.120 us; speedup vs baseline: 1.0358x; 1.0007x over previous
//
#include <hip/hip_runtime.h>

#define B_ 2
#define N_ 2048
#define H_ 8
#define DH_ 32
#define E_ 65536
#define DIN_ 256
#define KT 256
#define NKT (N_ / KT)
#define ECAP 32
#define QSCALE 0.2550348872f           // log2(e)/sqrt(DH)
#define LOG2E 1.4426950408889634f
#define LOG2MIN -19.931568569324174f   // log2(1e-6)

typedef short bf16x8 __attribute__((ext_vector_type(8)));
typedef float floatx4 __attribute__((ext_vector_type(4)));

__device__ __forceinline__ unsigned short f2b(float f){
  union { float f; unsigned int u; } v; v.f = f;
  return (unsigned short)((v.u + 0x7fffu + ((v.u >> 16) & 1u)) >> 16);
}
__device__ __forceinline__ bf16x8 f8_to_bf(const float* p){
  float4 a = *(const float4*)p, b = *(const float4*)(p + 4);
  bf16x8 r;
  r[0] = (short)f2b(a.x); r[1] = (short)f2b(a.y); r[2] = (short)f2b(a.z); r[3] = (short)f2b(a.w);
  r[4] = (short)f2b(b.x); r[5] = (short)f2b(b.y); r[6] = (short)f2b(b.z); r[7] = (short)f2b(b.w);
  return r;
}
__device__ __forceinline__ unsigned int cvt_pk_bf16(float lo, float hi){
  unsigned int r;
  asm("v_cvt_pk_bf16_f32 %0, %1, %2" : "=v"(r) : "v"(lo), "v"(hi));
  return r;
}
__device__ __forceinline__ float fexp2(float x){
  float r;
  asm("v_exp_f32 %0, %1" : "=v"(r) : "v"(x));
  return r;
}

// ---- prep: ffn (0..511) + fill (512..1023) + wT (1024..1279, coalesced writes) + x->bf16 (1280..1791) ----
__global__ __launch_bounds__(256) void prep_kernel(
    const float* __restrict__ eattr,
    const float* __restrict__ w1, const float* __restrict__ b1,
    const float* __restrict__ w2, const float* __restrict__ b2,
    float* __restrict__ ea,
    const int* __restrict__ ei, int* __restrict__ cnt, unsigned int* __restrict__ pck,
    const float* __restrict__ w, unsigned short* __restrict__ wT,
    const float* __restrict__ x, unsigned short* __restrict__ xb)
{
  int bb = blockIdx.x, tid = threadIdx.x;
  if (bb < 512){
    __shared__ float W1[64], W2[64], Bv1[8], Bv2[8];
    if (tid < 64){ W1[tid] = w1[tid]; W2[tid] = w2[tid]; }
    if (tid < 8){ Bv1[tid] = b1[tid]; Bv2[tid] = b2[tid]; }
    __syncthreads();
    int gid = bb * 256 + tid;                 // b*E + e
    const float* ep = eattr + (size_t)gid * 8;
    float cur[8];
#pragma unroll
    for (int i = 0; i < 8; ++i) cur[i] = ep[i];
#pragma unroll
    for (int pass = 0; pass < 2; ++pass){
      float t[8];
#pragma unroll
      for (int j = 0; j < 8; ++j){
        float s = Bv1[j];
#pragma unroll
        for (int i = 0; i < 8; ++i) s += cur[i] * W1[i * 8 + j];
        t[j] = fmaxf(s, 0.f);
      }
#pragma unroll
      for (int j = 0; j < 8; ++j){
        float s = Bv2[j];
#pragma unroll
        for (int i = 0; i < 8; ++i) s += t[i] * W2[i * 8 + j];
        cur[j] = s;
      }
    }
    float* op = ea + (size_t)gid * 8;
#pragma unroll
    for (int j = 0; j < 8; ++j) op[j] = cur[j] * LOG2E;   // exp2-domain
  } else if (bb < 1024){
    int gid = (bb - 512) * 256 + tid;         // 0..131071
    int b = gid >> 16, e = gid & (E_ - 1);
    int u = ei[(size_t)b * 2 * E_ + e];
    int v = ei[(size_t)b * 2 * E_ + E_ + e];
    int bucket = ((b << 11) + u) * 8 + (v >> 8);
    int slot = atomicAdd(&cnt[bucket], 1);
    if (slot < ECAP) pck[(size_t)bucket * ECAP + slot] = ((unsigned int)e << 11) | (unsigned int)v;
  } else if (bb < 1280){
    int c0 = (bb - 1024) * 3;
#pragma unroll
    for (int j = 0; j < 3; ++j){
      int c = c0 + j;
      wT[(size_t)c * 256 + tid] = f2b(w[(size_t)tid * 768 + c]);
    }
  } else {
    int gid = (bb - 1280) * 256 + tid;        // 0..131071
    bf16x8 v = f8_to_bf(x + (size_t)gid * 8);
    *(bf16x8*)(xb + (size_t)gid * 8) = v;
  }
}

// ---------------- QKV projection: bf16 A-input, MFMA; V staged via LDS for coalesced stores ----------------
__global__ __launch_bounds__(256) void qkv_kernel(
    const unsigned short* __restrict__ xb, const unsigned short* __restrict__ wT,
    const float* __restrict__ bias,
    unsigned short* __restrict__ Qb, unsigned short* __restrict__ Kb, unsigned short* __restrict__ Vt)
{
  __shared__ unsigned short vtile[64][20];   // 64 dh-cols x 16 n (+4 pad)
  int tid = threadIdx.x;
  int wave = tid >> 6, lane = tid & 63, m = lane & 15, quad = lane >> 4;
  int rowbase = blockIdx.x * 16;
  int colbase = blockIdx.y * 64 + wave * 16;
  floatx4 acc = {0.f, 0.f, 0.f, 0.f};
#pragma unroll
  for (int kb = 0; kb < 8; ++kb){
    bf16x8 af = *(const bf16x8*)(xb + (size_t)(rowbase + m) * DIN_ + kb * 32 + quad * 8);
    bf16x8 bf = *(const bf16x8*)(wT + (size_t)(colbase + m) * DIN_ + kb * 32 + quad * 8);
    acc = __builtin_amdgcn_mfma_f32_16x16x32_bf16(af, bf, acc, 0, 0, 0);
  }
  int ccol = colbase + m;
  int which = ccol >> 8, hh = (ccol >> 5) & 7, dh = ccol & 31;
  float bv = bias[ccol];
  int row0 = rowbase + quad * 4;
  int bidx = row0 >> 11, n0 = row0 & (N_ - 1);
  size_t bh = (size_t)(bidx * H_ + hh);
  if (which == 0){
#pragma unroll
    for (int r = 0; r < 4; ++r)
      Qb[(bh * N_ + n0 + r) * DH_ + dh] = f2b((acc[r] + bv) * QSCALE);
  } else if (which == 1){
#pragma unroll
    for (int r = 0; r < 4; ++r)
      Kb[(bh * N_ + n0 + r) * DH_ + dh] = f2b(acc[r] + bv);
  } else {
    int dh_b = wave * 16 + m;
    int n_l = quad * 4;
#pragma unroll
    for (int r = 0; r < 4; ++r)
      vtile[dh_b][n_l + r] = f2b(acc[r] + bv);
    __syncthreads();                        // block-uniform path (y-blocks 8..11 only)
    int dhb2 = tid >> 2;
    int ng = (tid & 3) * 4;
    int cc2 = blockIdx.y * 64 + dhb2;
    int hh2 = (cc2 >> 5) & 7, dh2 = cc2 & 31;
    int bidx2 = rowbase >> 11, nb2 = rowbase & (N_ - 1);
    ushort4 st = *(const ushort4*)&vtile[dhb2][ng];
    *(ushort4*)(Vt + ((size_t)((bidx2 * H_ + hh2) * DH_ + dh2)) * N_ + nb2 + ng) = st;
  }
}

// ---------------- fused flash attention: R9 base + defer-max skip (exact numerics) ----------------
// When a tile's max does not exceed the running max, al == 1 exactly and the whole rescale
// segment (exp2 -> 4 shfl broadcasts -> 8 multiplies, all on the serial path before PV) is a
// no-op: skip it behind a wave-uniform __all() branch. Numerics bit-identical to R9.
__global__ __launch_bounds__(128) void attn_kernel(
    const unsigned short* __restrict__ Qb, const unsigned short* __restrict__ Kb,
    const unsigned short* __restrict__ Vt, const float* __restrict__ adj,
    const float* __restrict__ ea, const int* __restrict__ cnt, const unsigned int* __restrict__ pck,
    const float* __restrict__ shifts, const float* __restrict__ widths,
    const float* __restrict__ selfW, float* __restrict__ out)
{
  __shared__ float S[2][16][260];         // per-wave 16x256 (+4 pad)

  int bid = blockIdx.x;                   // 0..1023
  int xcd = bid & 7, t = bid >> 3;        // t 0..127
  int hp = t & 3;                         // head pair 0..3
  int bqt = xcd * 32 + (t >> 2);          // 0..255
  int b = bqt >> 7, qt = bqt & 127;
  int qbase = qt * 16;
  int tid = threadIdx.x, wave = tid >> 6, lane = tid & 63, m = lane & 15, quad = lane >> 4;
  int h = hp * 2 + wave;
  float shift_h = shifts[h];
  float w_h = widths[h];
  float i2w_h = LOG2E / (2.f * w_h * w_h);
  float selfW_h = selfW[h] * LOG2E;
  size_t krow = (size_t)(b * H_ + h) * N_;
  size_t vrow = (size_t)(b * H_ + h) * DH_;
  bf16x8 qfrag = *(const bf16x8*)(Qb + (krow + qbase + m) * DH_ + quad * 8);
  float (*Sw)[260] = S[wave];

  int rr = lane >> 2, sl0 = lane & 3;     // scatter: 4 lanes per q-row
  const int* cntp = cnt + ((size_t)(b * N_) + qbase + rr) * 8;
  const unsigned int* pckp = pck + ((size_t)((b * N_ + qbase + rr) * 8)) * ECAP;
  const float* eabase = ea + (size_t)b * E_ * H_ + h;
  const float* adjp = adj + ((size_t)b * N_ + qbase + m) * N_ + quad * 8;
  const unsigned short* vp0 = Vt + (vrow + m) * N_ + quad * 8;
  const unsigned short* vp1 = Vt + (vrow + 16 + m) * N_ + quad * 8;
  const unsigned short* kp  = Kb + (krow + m) * DH_ + quad * 8;

  floatx4 sh4 = {shift_h, shift_h, shift_h, shift_h};
  floatx4 ni4 = {-i2w_h, -i2w_h, -i2w_h, -i2w_h};
  floatx4 lm4 = {LOG2MIN, LOG2MIN, LOG2MIN, LOG2MIN};
  floatx4 z4  = {0.f, 0.f, 0.f, 0.f};

  float mcur = -1e30f, lcur = 0.f;
  floatx4 oacc0 = z4, oacc1 = z4;

  // ---- scatter pipeline prologue (tile 0) ----
  int nb_c = cntp[0]; nb_c = nb_c > ECAP ? ECAP : nb_c;
  unsigned int pk0 = pckp[sl0];
  unsigned int pk1 = pckp[sl0 + 4];
  int vv0_c = (int)(pk0 & (N_ - 1));
  int vv1_c = (int)(pk1 & (N_ - 1));
  bool g0_c = (sl0 < nb_c);
  bool g1_c = (sl0 + 4 < nb_c);
  float ea0_c = 0.f, ea1_c = 0.f;
  if (g0_c) ea0_c = eabase[(size_t)(pk0 >> 11) * H_];
  if (g1_c) ea1_c = eabase[(size_t)(pk1 >> 11) * H_];

#pragma unroll 2
  for (int kt = 0; kt < NKT; ++kt){
    int k0 = kt * KT;
    // ---- prefetch next-tile scatter metadata ----
    int nb_n = 0; unsigned int pk0_n = 0, pk1_n = 0;
    if (kt + 1 < NKT){
      nb_n  = cntp[kt + 1];
      pk0_n = pckp[(kt + 1) * ECAP + sl0];
      pk1_n = pckp[(kt + 1) * ECAP + sl0 + 4];
    }
    // ---- QK^T: full 256 cols x 16 rows (4 col-blocks) ----
#pragma unroll
    for (int cb = 0; cb < 4; ++cb){
      const unsigned short* kpb = kp + (size_t)(k0 + cb * 64) * DH_;
#pragma unroll
      for (int s = 0; s < 4; ++s){
        bf16x8 kf = *(const bf16x8*)(kpb + (size_t)(s * 16) * DH_);
        floatx4 acc = __builtin_amdgcn_mfma_f32_16x16x32_bf16(qfrag, kf, z4, 0, 0, 0);
#pragma unroll
        for (int r = 0; r < 4; ++r)
          Sw[quad * 4 + r][cb * 64 + s * 16 + m] = acc[r];
      }
    }
    // ---- diagonal self-loop fixup ----
    {
      int dw = qbase - k0;
      if ((unsigned)dw < 256u && lane < 16)
        Sw[lane][dw + lane] += selfW_h;
    }
    // ---- scatter apply (ea preloaded one tile ago) ----
    if (g0_c) Sw[rr][vv0_c - k0] += ea0_c;
    if (g1_c) Sw[rr][vv1_c - k0] += ea1_c;
    if (nb_c > 8){                          // rare overflow (Poisson tail)
      for (int slot = sl0 + 8; slot < nb_c; slot += 4){
        unsigned int p = pckp[kt * ECAP + slot];
        Sw[rr][(int)(p & (N_ - 1)) - k0] += eabase[(size_t)(p >> 11) * H_];
      }
    }
    // ---- issue guarded ea loads for next tile ----
    int vv0_n = 0, vv1_n = 0; bool g0_n = false, g1_n = false;
    float ea0_n = 0.f, ea1_n = 0.f;
    if (kt + 1 < NKT){
      nb_n = nb_n > ECAP ? ECAP : nb_n;
      vv0_n = (int)(pk0_n & (N_ - 1));
      vv1_n = (int)(pk1_n & (N_ - 1));
      g0_n = (sl0 < nb_n);
      g1_n = (sl0 + 4 < nb_n);
      if (g0_n) ea0_n = eabase[(size_t)(pk0_n >> 11) * H_];
      if (g1_n) ea1_n = eabase[(size_t)(pk1_n >> 11) * H_];
    }
    // ---- S rows to regs + moire, all 4 col-blocks ----
    floatx4 sv[4][4];
#pragma unroll
    for (int cb = 0; cb < 4; ++cb){
      const float* sp = &Sw[m][cb * 64 + quad * 8];
      sv[cb][0] = *(const floatx4*)(sp);
      sv[cb][1] = *(const floatx4*)(sp + 4);
      sv[cb][2] = *(const floatx4*)(sp + 32);
      sv[cb][3] = *(const floatx4*)(sp + 36);
      const float* ap = adjp + k0 + cb * 64;
      floatx4 a0 = *(const floatx4*)(ap);
      floatx4 a1 = *(const floatx4*)(ap + 4);
      floatx4 a2 = *(const floatx4*)(ap + 32);
      floatx4 a3 = *(const floatx4*)(ap + 36);
      floatx4 d;
      d = a0 - sh4; sv[cb][0] += __builtin_elementwise_max(d * d * ni4, lm4);
      d = a1 - sh4; sv[cb][1] += __builtin_elementwise_max(d * d * ni4, lm4);
      d = a2 - sh4; sv[cb][2] += __builtin_elementwise_max(d * d * ni4, lm4);
      d = a3 - sh4; sv[cb][3] += __builtin_elementwise_max(d * d * ni4, lm4);
    }
    // ---- row max over all 256 cols ----
    floatx4 mx01 = __builtin_elementwise_max(
        __builtin_elementwise_max(sv[0][0], sv[0][1]),
        __builtin_elementwise_max(sv[0][2], sv[0][3]));
    floatx4 mx23 = __builtin_elementwise_max(
        __builtin_elementwise_max(sv[1][0], sv[1][1]),
        __builtin_elementwise_max(sv[1][2], sv[1][3]));
    floatx4 mx45 = __builtin_elementwise_max(
        __builtin_elementwise_max(sv[2][0], sv[2][1]),
        __builtin_elementwise_max(sv[2][2], sv[2][3]));
    floatx4 mx67 = __builtin_elementwise_max(
        __builtin_elementwise_max(sv[3][0], sv[3][1]),
        __builtin_elementwise_max(sv[3][2], sv[3][3]));
    floatx4 mxv = __builtin_elementwise_max(__builtin_elementwise_max(mx01, mx23),
                                            __builtin_elementwise_max(mx45, mx67));
    float lm = fmaxf(fmaxf(mxv.x, mxv.y), fmaxf(mxv.z, mxv.w));
    lm = fmaxf(lm, __shfl_xor(lm, 16));
    lm = fmaxf(lm, __shfl_xor(lm, 32));
    // ---- defer-max skip: if no row in this wave has a new max, al == 1 exactly ----
    float al = 1.f;
    if (!__all(lm <= mcur)){
      float mnew = fmaxf(mcur, lm);
      al = fexp2(mcur - mnew);
      mcur = mnew;
      float al0 = __shfl(al, quad * 4 + 0);
      float al1 = __shfl(al, quad * 4 + 1);
      float al2 = __shfl(al, quad * 4 + 2);
      float al3 = __shfl(al, quad * 4 + 3);
      oacc0[0] *= al0; oacc0[1] *= al1; oacc0[2] *= al2; oacc0[3] *= al3;
      oacc1[0] *= al0; oacc1[1] *= al1; oacc1[2] *= al2; oacc1[3] *= al3;
    }
    // ---- P = exp2(S - m), pack, PV MFMA per col-block; lane-partial row sum ----
    floatx4 m4 = {mcur, mcur, mcur, mcur};
    floatx4 psv = z4;
#pragma unroll
    for (int cb = 0; cb < 4; ++cb){
      const unsigned short* vA = vp0 + k0 + cb * 64;
      const unsigned short* vB = vp1 + k0 + cb * 64;
      bf16x8 vf00 = *(const bf16x8*)(vA);
      bf16x8 vf01 = *(const bf16x8*)(vB);
      bf16x8 vf10 = *(const bf16x8*)(vA + 32);
      bf16x8 vf11 = *(const bf16x8*)(vB + 32);
      floatx4 e0 = sv[cb][0] - m4, e1 = sv[cb][1] - m4;
      floatx4 e2 = sv[cb][2] - m4, e3 = sv[cb][3] - m4;
      floatx4 p0, p1, p2, p3;
      p0.x = fexp2(e0.x); p0.y = fexp2(e0.y); p0.z = fexp2(e0.z); p0.w = fexp2(e0.w);
      p1.x = fexp2(e1.x); p1.y = fexp2(e1.y); p1.z = fexp2(e1.z); p1.w = fexp2(e1.w);
      p2.x = fexp2(e2.x); p2.y = fexp2(e2.y); p2.z = fexp2(e2.z); p2.w = fexp2(e2.w);
      p3.x = fexp2(e3.x); p3.y = fexp2(e3.y); p3.z = fexp2(e3.z); p3.w = fexp2(e3.w);
      psv += (p0 + p1) + (p2 + p3);
      union { bf16x8 v; unsigned int u[4]; } PL, PH;
      PL.u[0] = cvt_pk_bf16(p0.x, p0.y); PL.u[1] = cvt_pk_bf16(p0.z, p0.w);
      PL.u[2] = cvt_pk_bf16(p1.x, p1.y); PL.u[3] = cvt_pk_bf16(p1.z, p1.w);
      PH.u[0] = cvt_pk_bf16(p2.x, p2.y); PH.u[1] = cvt_pk_bf16(p2.z, p2.w);
      PH.u[2] = cvt_pk_bf16(p3.x, p3.y); PH.u[3] = cvt_pk_bf16(p3.z, p3.w);
      oacc0 = __builtin_amdgcn_mfma_f32_16x16x32_bf16(PL.v, vf00, oacc0, 0, 0, 0);
      oacc1 = __builtin_amdgcn_mfma_f32_16x16x32_bf16(PL.v, vf01, oacc1, 0, 0, 0);
      oacc0 = __builtin_amdgcn_mfma_f32_16x16x32_bf16(PH.v, vf10, oacc0, 0, 0, 0);
      oacc1 = __builtin_amdgcn_mfma_f32_16x16x32_bf16(PH.v, vf11, oacc1, 0, 0, 0);
    }
    float ps = (psv.x + psv.y) + (psv.z + psv.w);
    ps += __shfl_xor(ps, 16);
    ps += __shfl_xor(ps, 32);
    lcur = lcur * al + ps;
    // ---- rotate scatter pipeline ----
    nb_c = nb_n; g0_c = g0_n; g1_c = g1_n;
    vv0_c = vv0_n; vv1_c = vv1_n; ea0_c = ea0_n; ea1_c = ea1_n;
  }

  // ---- direct output (wave owns full rows: no merge, no barrier) ----
  float linv0 = 1.f / __shfl(lcur, quad * 4 + 0);
  float linv1 = 1.f / __shfl(lcur, quad * 4 + 1);
  float linv2 = 1.f / __shfl(lcur, quad * 4 + 2);
  float linv3 = 1.f / __shfl(lcur, quad * 4 + 3);
  float* ob = out + ((size_t)b * N_ + qbase + quad * 4) * (H_ * DH_) + h * DH_;
  ob[0 * H_ * DH_ + m]      = oacc0[0] * linv0;
  ob[0 * H_ * DH_ + 16 + m] = oacc1[0] * linv0;
  ob[1 * H_ * DH_ + m]      = oacc0[1] * linv1;
  ob[1 * H_ * DH_ + 16 + m] = oacc1[1] * linv1;
  ob[2 * H_ * DH_ + m]      = oacc0[2] * linv2;
  ob[2 * H_ * DH_ + 16 + m] = oacc1[2] * linv2;
  ob[3 * H_ * DH_ + m]      = oacc0[3] * linv3;
  ob[3 * H_ * DH_ + 16 + m] = oacc1[3] * linv3;
}

extern "C" void kernel_launch(void* const* d_in, const int* in_sizes, int n_in,
                              void* d_out, int out_size, void* d_ws, size_t ws_size,
                              hipStream_t stream)
{
  const float* x      = (const float*)d_in[0];
  const float* adj    = (const float*)d_in[1];
  const float* eattr  = (const float*)d_in[2];
  const float* qkvw   = (const float*)d_in[3];
  const float* qkvb   = (const float*)d_in[4];
  const float* ew1    = (const float*)d_in[5];
  const float* eb1    = (const float*)d_in[6];
  const float* ew2    = (const float*)d_in[7];
  const float* eb2    = (const float*)d_in[8];
  const float* shifts = (const float*)d_in[9];
  const float* widths = (const float*)d_in[10];
  const float* selfW  = (const float*)d_in[11];
  const int*   ei     = (const int*)d_in[12];
  float* out = (float*)d_out;

  char* ws = (char*)d_ws;
  unsigned short* Qb  = (unsigned short*)(ws);                        // 2 MB
  unsigned short* Kb  = (unsigned short*)(ws + ((size_t)2 << 20));    // 2 MB
  unsigned short* Vt  = (unsigned short*)(ws + ((size_t)4 << 20));    // 2 MB
  unsigned short* wT  = (unsigned short*)(ws + ((size_t)6 << 20));    // 384 KB
  float*          ea  = (float*)(ws + ((size_t)7 << 20));             // 4 MB
  int*            cnt = (int*)(ws + ((size_t)11 << 20));              // 128 KB
  unsigned int*  pck  = (unsigned int*)(ws + ((size_t)12 << 20));     // 4 MB
  unsigned short* xb  = (unsigned short*)(ws + ((size_t)16 << 20));   // 2 MB (total 18 MB)

  hipMemsetAsync(cnt, 0, (size_t)B_ * N_ * 8 * sizeof(int), stream);
  hipLaunchKernelGGL(prep_kernel, dim3(1792), dim3(256), 0, stream,
                     eattr, ew1, eb1, ew2, eb2, ea, ei, cnt, pck, qkvw, wT, x, xb);
  hipLaunchKernelGGL(qkv_kernel, dim3(256, 12), dim3(256), 0, stream, xb, wT, qkvb, Qb, Kb, Vt);
  hipLaunchKernelGGL(attn_kernel, dim3(B_ * (H_ / 2) * (N_ / 16)), dim3(128), 0, stream,
                     Qb, Kb, Vt, adj, ea, cnt, pck, shifts, widths, selfW, out);
}